// Round 4
// baseline (3270.482 us; speedup 1.0000x reference)
//
#include <hip/hip_runtime.h>
#include <hip/hip_bf16.h>

#define B_ 8
#define S_ 4096
#define F_ 256
#define I_ 512
#define D_ 4
#define K_ 7
#define V_ 256
#define I3_ 1536
#define KE_ 3584           // 7*512 flattened causal-conv K
#define VR_ (S_ + 8)       // vbt rows: 6 zero-pad + 4096 + 2 slack

using bf16 = __hip_bfloat16;
typedef __bf16 bf16x8 __attribute__((ext_vector_type(8)));
typedef float  f32x4  __attribute__((ext_vector_type(4)));

#define LDS_PTR(p) ((__attribute__((address_space(3))) void*)(p))
#define GLB_PTR(p) ((const __attribute__((address_space(1))) void*)(p))

// mish(x) = x*tanh(softplus(x)) = x*(u^2+2u)/(u^2+2u+2), u=e^x (exact closed form).
// Clamp exp arg at 30: t=1.1e26 (no overflow), ratio==1 in fp32, matching tanh->1.
__device__ __forceinline__ float mishf(float x) {
    float u = expf(fminf(x, 30.0f));
    float t = u * (u + 2.0f);
    return x * (t / (t + 2.0f));
}

__device__ __forceinline__ float loadw(const void* p, size_t i, int isbf) {
    return isbf ? __bfloat162float(((const bf16*)p)[i]) : ((const float*)p)[i];
}

__device__ __forceinline__ __bf16 tobf(float x) {
    bf16 h = __float2bfloat16(x);
    return *(__bf16*)&h;
}

// bf16 buffers of small weights never show bf16-exponent>=132 (|x|>=32);
// fp32 buffers read as uint16 do (random mantissa bits in low halves).
__global__ __launch_bounds__(256)
void detect_kernel(int* __restrict__ flag, const unsigned short* __restrict__ p)
{
    __shared__ int sh[256];
    int cnt = 0;
    for (int j = threadIdx.x; j < 16384; j += 256) {
        unsigned int e = (p[j] >> 7) & 0xffu;
        if (e >= 132u) cnt++;
    }
    sh[threadIdx.x] = cnt;
    __syncthreads();
    for (int s = 128; s > 0; s >>= 1) {
        if ((int)threadIdx.x < s) sh[threadIdx.x] += sh[threadIdx.x + s];
        __syncthreads();
    }
    if (threadIdx.x == 0) flag[0] = (sh[0] == 0) ? 1 : 0;   // 1 => bf16 inputs
}

__global__ __launch_bounds__(256)
void embed_kernel(float* __restrict__ x0, float* __restrict__ x1,
                  const int* __restrict__ inp, const void* __restrict__ emb,
                  const int* __restrict__ flag)
{
    const int isbf = flag[0];
    size_t idx = (size_t)blockIdx.x * 256 + threadIdx.x;   // over B*F*S
    int s = (int)(idx % S_);
    int f = (int)((idx / S_) % F_);
    int b = (int)(idx / ((size_t)S_ * F_));
    int tok = inp[b * S_ + s];
    x0[idx] = loadw(emb, (size_t)tok * (2 * F_) + f, isbf);
    x1[idx] = loadw(emb, (size_t)tok * (2 * F_) + F_ + f, isbf);
}

// generic dtype-cast copy: dst[i] = (bf16)src[soff + i]
__global__ __launch_bounds__(256)
void cvt_kernel(bf16* __restrict__ dst, const void* __restrict__ src,
                size_t soff, int n, const int* __restrict__ flag)
{
    const int isbf = flag[0];
    int i = blockIdx.x * 256 + threadIdx.x;
    if (i < n) dst[i] = __float2bfloat16(loadw(src, soff + i, isbf));
}

// zero the 6 pad rows of all P vbt slices (re-poisoned every call)
__global__ __launch_bounds__(256)
void zeropad_kernel(bf16* __restrict__ vbt, int nslice)
{
    int i = blockIdx.x * 256 + threadIdx.x;
    if (i < nslice * 6 * I_) {
        int z = i / (6 * I_), off = i % (6 * I_);
        vbt[(size_t)z * VR_ * I_ + off] = __float2bfloat16(0.0f);
    }
}

// Inputs t are PRE-MISHED by the gemm epilogue.
// v[i,s] = cumsum_s(t[i,s])/(s+1) * t[I+i,s] + t[2I+i,s]; bf16 output.
// grid (I_, P): blockIdx.y = z scratch slice
__global__ __launch_bounds__(256)
void scan_kernel(bf16* __restrict__ vout, const float* __restrict__ t)
{
    const int z = blockIdx.y;
    const int i = blockIdx.x;
    t    += (size_t)z * I3_ * S_;
    vout += (size_t)z * I_ * S_;
    const float* dp  = t + (size_t)i * S_;
    const float* scp = dp + (size_t)I_ * S_;
    const float* shp = dp + (size_t)(2 * I_) * S_;
    bf16* op = vout + (size_t)i * S_;
    const int tid = threadIdx.x;
    const int base = tid * 16;

    float md[16];
    float lsum = 0.f;
    #pragma unroll
    for (int q = 0; q < 4; ++q) {
        float4 dv = *(const float4*)(dp + base + q * 4);
        #pragma unroll
        for (int j = 0; j < 4; ++j) {
            float m = (&dv.x)[j];
            md[q * 4 + j] = m;
            lsum += m;
        }
    }
    float ssum = lsum;
    #pragma unroll
    for (int off = 1; off < 64; off <<= 1) {
        float nv = __shfl_up(ssum, off, 64);
        if ((tid & 63) >= off) ssum += nv;
    }
    __shared__ float wtot[4];
    const int wid = tid >> 6, lane = tid & 63;
    if (lane == 63) wtot[wid] = ssum;
    __syncthreads();
    float excl = ssum - lsum;
    #pragma unroll
    for (int wq = 0; wq < 3; ++wq)
        if (wq < wid) excl += wtot[wq];

    float run = excl;
    bf16x8 o0v, o1v;
    #pragma unroll
    for (int q = 0; q < 4; ++q) {
        float4 scv = *(const float4*)(scp + base + q * 4);
        float4 shv = *(const float4*)(shp + base + q * 4);
        #pragma unroll
        for (int j = 0; j < 4; ++j) {
            run += md[q * 4 + j];
            float sdiv = (float)(base + q * 4 + j + 1);
            float ov = run / sdiv * (&scv.x)[j] + (&shv.x)[j];
            if (q < 2) o0v[q * 4 + j] = tobf(ov);
            else       o1v[(q - 2) * 4 + j] = tobf(ov);
        }
    }
    *(bf16x8*)(void*)(op + base) = o0v;
    *(bf16x8*)(void*)(op + base + 8) = o1v;
}

// w1 [o][c][k] (k innermost) -> wexp [o][k*512+c] bf16 (flattened-K A matrix)
__global__ __launch_bounds__(256)
void wexp_kernel(bf16* __restrict__ wexp, const void* __restrict__ w1,
                 size_t woff, const int* __restrict__ flag)
{
    const int isbf = flag[0];
    int idx = blockIdx.x * 256 + threadIdx.x;      // over 1536*512
    int c = idx & 511, o = idx >> 9;
    const size_t base = woff + ((size_t)o * 512 + c) * 7;
    float vals[7];
    #pragma unroll
    for (int k = 0; k < 7; ++k) vals[k] = loadw(w1, base + k, isbf);
    #pragma unroll
    for (int k = 0; k < 7; ++k)
        wexp[(size_t)o * KE_ + (k << 9) + c] = __float2bfloat16(vals[k]);
}

// src fp32 [C][S_] (+z*szstr) -> dst bf16 [S_][C] (+z*dzstr); 64x64 LDS tile
__global__ __launch_bounds__(256)
void trans_kernel(bf16* __restrict__ dst, size_t dzstr,
                  const float* __restrict__ src, size_t szstr, int C)
{
    __shared__ __align__(16) bf16 lt[64][72];
    const int z = blockIdx.z;
    dst += (size_t)z * dzstr;
    src += (size_t)z * szstr;
    const int tid = threadIdx.x;
    const int s0 = blockIdx.x * 64;
    const int c0 = blockIdx.y * 64;
    #pragma unroll
    for (int p = 0; p < 4; ++p) {
        int c = p * 16 + (tid >> 4);
        int sc = (tid & 15) * 4;
        float4 f = *(const float4*)(src + (size_t)(c0 + c) * S_ + s0 + sc);
        #pragma unroll
        for (int j = 0; j < 4; ++j)
            lt[sc + j][c] = __float2bfloat16((&f.x)[j]);
    }
    __syncthreads();
    #pragma unroll
    for (int p = 0; p < 2; ++p) {
        int ch = p * 256 + tid;
        int r = ch >> 3, g = ch & 7;
        *(bf16x8*)(dst + (size_t)(s0 + r) * C + c0 + g * 8) =
            *(const bf16x8*)&lt[r][g * 8];
    }
}

// src bf16 [C][S_] (+z*szstr) -> dst bf16 [S_][C] (+z*dzstr); 64x64 LDS tile
__global__ __launch_bounds__(256)
void transb_kernel(bf16* __restrict__ dst, size_t dzstr,
                   const bf16* __restrict__ src, size_t szstr, int C)
{
    __shared__ __align__(16) bf16 lt[64][72];
    const int z = blockIdx.z;
    dst += (size_t)z * dzstr;
    src += (size_t)z * szstr;
    const int tid = threadIdx.x;
    const int s0 = blockIdx.x * 64;
    const int c0 = blockIdx.y * 64;
    #pragma unroll
    for (int p = 0; p < 2; ++p) {
        int c = p * 32 + (tid >> 3);
        int sc = (tid & 7) * 8;
        bf16x8 v = *(const bf16x8*)(src + (size_t)(c0 + c) * S_ + s0 + sc);
        #pragma unroll
        for (int j = 0; j < 8; ++j)
            *(__bf16*)&lt[sc + j][c] = v[j];
    }
    __syncthreads();
    #pragma unroll
    for (int p = 0; p < 2; ++p) {
        int ch = p * 256 + tid;
        int r = ch >> 3, g = ch & 7;
        *(bf16x8*)(dst + (size_t)(s0 + r) * C + c0 + g * 8) =
            *(const bf16x8*)&lt[r][g * 8];
    }
}

// ---------------------------------------------------------------------------
// 128(o) x 256(s) tile GEMM, tri-buffered LDS, ONE barrier per K-tile (BK=64).
// Grid = 16 x 12 x P = 768 (P=4): exact 3 rounds over 256 CUs.
// out[o,s] = sum_k Aw[o*lda+k] * B(s,k); conv=1: B(s,k)=Bm[(s+(k>>9))*ldb+(k&511)].
// 512 thr = 8 waves (2M x 4N); per-wave 64o x 64s; acc[4][4].
// Per K-tile t (buf b=t%3): issue 6 stage loads for tile t+2 -> buf (t+2)%3;
// ds_read all 16 frags of buf b (compiler inserts fine-grained lgkmcnt);
// 32 MFMA; vmcnt(6) (drains tile t+1's 6 loads, issued a full tile earlier);
// s_barrier. Correctness with a single barrier:
//  WAR: buf (t+2)%3's last readers are tile t-1's ds_reads, complete before
//       each wave's own lgkm wait and the t-1 end-barrier; restage is issued
//       after that barrier.
//  RAW: per-wave vmcnt(6) before the barrier lands that wave's t+1 DMA
//       portions; the barrier publishes all waves' portions before any read.
// No mid-tile barrier => waves skew freely; LDS unit + MFMA pipe + VMEM all
// stay fed across the whole tile instead of draining at phase boundaries.
// domish: fused mish on the fp32 result (feeds scan_kernel).
// ---------------------------------------------------------------------------
__global__ __launch_bounds__(512, 2)
void gemm128x256_kernel(float* __restrict__ out, size_t ozstr,
                        const bf16* __restrict__ Aw, int lda,
                        const bf16* __restrict__ Bm, size_t bzstr, int ldb,
                        int Kdim, int conv, int domish)
{
    __shared__ __align__(16) bf16 la[3][128][64];   // 48 KiB
    __shared__ __align__(16) bf16 lb[3][256][64];   // 96 KiB
    const int tid = threadIdx.x;
    const int s0 = blockIdx.x * 256;
    const int o0 = blockIdx.y * 128;
    const int z  = blockIdx.z;
    out += (size_t)z * ozstr;
    Bm  += (size_t)z * bzstr;
    const int wv = tid >> 6, lane = tid & 63;
    const int wr = wv >> 2, wc = wv & 3;            // 2(M) x 4(N) waves
    const int l16 = lane & 15, q = lane >> 4;
    const int srow = lane >> 3;                     // staging row within 8-row strip
    const int schunk = (lane & 7) ^ srow;           // pre-swizzled source chunk
    const int nKt = Kdim >> 6;

    f32x4 acc[4][4];
    #pragma unroll
    for (int i = 0; i < 4; ++i)
        #pragma unroll
        for (int j = 0; j < 4; ++j)
            #pragma unroll
            for (int r = 0; r < 4; ++r) acc[i][j][r] = 0.f;

#define STAGE_A3(buf, kt) do {                                                \
    const bf16* gpA_ = Aw + (size_t)(o0 + wv * 8 + srow) * lda                \
                          + ((kt) << 6) + (schunk << 3);                      \
    __builtin_amdgcn_global_load_lds(GLB_PTR(gpA_),                           \
        LDS_PTR(&la[buf][wv * 8][0]), 16, 0, 0);                              \
    __builtin_amdgcn_global_load_lds(GLB_PTR(gpA_ + (size_t)64 * lda),        \
        LDS_PTR(&la[buf][64 + wv * 8][0]), 16, 0, 0);                         \
} while (0)

#define STAGE_BL(buf, l, ro, bk) do {                                         \
    const bf16* gpB_ = Bm + (size_t)(s0 + (l) * 64 + wv * 8 + srow + (ro)) * ldb \
                          + (bk) + (schunk << 3);                             \
    __builtin_amdgcn_global_load_lds(GLB_PTR(gpB_),                           \
        LDS_PTR(&lb[buf][(l) * 64 + wv * 8][0]), 16, 0, 0);                   \
} while (0)

#define LDAF8(buf) do {                                                       \
    _Pragma("unroll") for (int i2 = 0; i2 < 4; ++i2)                          \
    _Pragma("unroll") for (int kk = 0; kk < 2; ++kk) {                        \
        int r_ = wr * 64 + i2 * 16 + l16;                                     \
        af[i2 * 2 + kk] =                                                     \
            *(const bf16x8*)&la[buf][r_][((kk * 4 + q) ^ (r_ & 7)) << 3];     \
    }                                                                         \
} while (0)

#define LDBF8(buf) do {                                                       \
    _Pragma("unroll") for (int j2 = 0; j2 < 4; ++j2)                          \
    _Pragma("unroll") for (int kk = 0; kk < 2; ++kk) {                        \
        int r_ = wc * 64 + j2 * 16 + l16;                                     \
        bfr[j2 * 2 + kk] =                                                    \
            *(const bf16x8*)&lb[buf][r_][((kk * 4 + q) ^ (r_ & 7)) << 3];     \
    }                                                                         \
} while (0)

#define MFMA32() do {                                                         \
    __builtin_amdgcn_s_setprio(1);                                            \
    _Pragma("unroll") for (int kk = 0; kk < 2; ++kk)                          \
    _Pragma("unroll") for (int i2 = 0; i2 < 4; ++i2)                          \
    _Pragma("unroll") for (int j2 = 0; j2 < 4; ++j2)                          \
        acc[i2][j2] = __builtin_amdgcn_mfma_f32_16x16x32_bf16(                \
            af[i2 * 2 + kk], bfr[j2 * 2 + kk], acc[i2][j2], 0, 0, 0);         \
    __builtin_amdgcn_s_setprio(0);                                            \
} while (0)

#define BARR()  __builtin_amdgcn_s_barrier()
#define WVM6()  asm volatile("s_waitcnt vmcnt(6)" ::: "memory")
#define WVM0()  asm volatile("s_waitcnt vmcnt(0)" ::: "memory")

    // prologue: stage tiles 0 -> buf0, 1 -> buf1 (6 loads each)
    STAGE_A3(0, 0);
    STAGE_BL(0, 0, 0, 0); STAGE_BL(0, 1, 0, 0);
    STAGE_BL(0, 2, 0, 0); STAGE_BL(0, 3, 0, 0);
    STAGE_A3(1, 1);                                   // k0=64: ro=0, bk=64 (conv too)
    STAGE_BL(1, 0, 0, 64); STAGE_BL(1, 1, 0, 64);
    STAGE_BL(1, 2, 0, 64); STAGE_BL(1, 3, 0, 64);
    WVM6();                  // tile0's 6 loads landed; tile1's 6 may fly
    BARR();

    bf16x8 af[8], bfr[8];
    int b = 0;
    for (int t = 0; t < nKt; ++t) {
        int b2 = b + 2; if (b2 >= 3) b2 -= 3;         // (t+2)%3
        const bool st = (t + 2) < nKt;
        int ro2 = 0, bk2 = (t + 2) << 6;
        if (conv) { ro2 = bk2 >> 9; bk2 &= 511; }
        // issue next-next tile's 6 stage loads first (starts HBM early)
        if (st) {
            STAGE_A3(b2, t + 2);
            STAGE_BL(b2, 0, ro2, bk2); STAGE_BL(b2, 1, ro2, bk2);
            STAGE_BL(b2, 2, ro2, bk2); STAGE_BL(b2, 3, ro2, bk2);
        }
        // all 16 fragment reads for this tile (compiler schedules lgkmcnt)
        LDAF8(b); LDBF8(b);
        MFMA32();
        if (st) { WVM6(); } else { WVM0(); }          // tile t+1 fully landed
        BARR();
        b += 1; if (b >= 3) b = 0;
    }

    // C/D: col(lane&15)=s, row(q*4+reg)=o   [verified convention]
    #pragma unroll
    for (int i = 0; i < 4; ++i)
        #pragma unroll
        for (int j = 0; j < 4; ++j) {
            int sg = s0 + wc * 64 + j * 16 + l16;
            #pragma unroll
            for (int r = 0; r < 4; ++r) {
                int og = o0 + wr * 64 + i * 16 + q * 4 + r;
                float v = acc[i][j][r];
                if (domish) v = mishf(v);
                out[(size_t)og * S_ + sg] = v;
            }
        }
#undef STAGE_A3
#undef STAGE_BL
#undef LDAF8
#undef LDBF8
#undef MFMA32
#undef BARR
#undef WVM6
#undef WVM0
}

// 128x128 GEMM (m97 structure) kept for the small w2 conv (M=256) + accumulate.
__global__ __launch_bounds__(256)
void gemm128_kernel(float* __restrict__ out, size_t ozstr,
                    const bf16* __restrict__ Aw, int lda,
                    const bf16* __restrict__ Bm, size_t bzstr, int ldb,
                    int Kdim, int conv, int addres)
{
    __shared__ __align__(16) bf16 la[128][64];
    __shared__ __align__(16) bf16 lb[128][64];
    const int tid = threadIdx.x;
    const int s0 = blockIdx.x * 128;
    const int o0 = blockIdx.y * 128;
    const int z  = blockIdx.z;
    out += (size_t)z * ozstr;
    Bm  += (size_t)z * bzstr;
    const int wv = tid >> 6, lane = tid & 63;
    const int wo = wv & 1, wsv = wv >> 1;
    const int l16 = lane & 15, q = lane >> 4;
    const int lrow = lane >> 3, lslot = lane & 7;

    f32x4 acc[4][4];
    #pragma unroll
    for (int i = 0; i < 4; ++i)
        #pragma unroll
        for (int j = 0; j < 4; ++j)
            #pragma unroll
            for (int r = 0; r < 4; ++r) acc[i][j][r] = 0.f;

    for (int k0 = 0; k0 < Kdim; k0 += 64) {
        int roff = 0, bk = k0;
        if (conv) { roff = k0 >> 9; bk = k0 & 511; }
        __syncthreads();
        #pragma unroll
        for (int t = 0; t < 4; ++t) {
            int rbase = wv * 32 + t * 8;
            int row = rbase + lrow;
            int chunk = lslot ^ (row & 7);
            __builtin_amdgcn_global_load_lds(
                GLB_PTR(Aw + (size_t)(o0 + row) * lda + k0 + chunk * 8),
                LDS_PTR(&la[rbase][0]), 16, 0, 0);
        }
        #pragma unroll
        for (int t = 0; t < 4; ++t) {
            int rbase = wv * 32 + t * 8;
            int row = rbase + lrow;
            int chunk = lslot ^ (row & 7);
            __builtin_amdgcn_global_load_lds(
                GLB_PTR(Bm + (size_t)(s0 + row + roff) * ldb + bk + chunk * 8),
                LDS_PTR(&lb[rbase][0]), 16, 0, 0);
        }
        __syncthreads();
        #pragma unroll
        for (int kk = 0; kk < 2; ++kk) {
            bf16x8 af[4], bfr[4];
            #pragma unroll
            for (int i = 0; i < 4; ++i) {
                int r = wo * 64 + i * 16 + l16;
                int c = kk * 4 + q;
                af[i] = *(const bf16x8*)&la[r][(c ^ (r & 7)) * 8];
            }
            #pragma unroll
            for (int j = 0; j < 4; ++j) {
                int r = wsv * 64 + j * 16 + l16;
                int c = kk * 4 + q;
                bfr[j] = *(const bf16x8*)&lb[r][(c ^ (r & 7)) * 8];
            }
            #pragma unroll
            for (int i = 0; i < 4; ++i)
                #pragma unroll
                for (int j = 0; j < 4; ++j)
                    acc[i][j] = __builtin_amdgcn_mfma_f32_16x16x32_bf16(
                        af[i], bfr[j], acc[i][j], 0, 0, 0);
        }
    }
    #pragma unroll
    for (int i = 0; i < 4; ++i)
        #pragma unroll
        for (int j = 0; j < 4; ++j) {
            int sg = s0 + wsv * 64 + j * 16 + l16;
            #pragma unroll
            for (int r = 0; r < 4; ++r) {
                int og = o0 + wo * 64 + i * 16 + q * 4 + r;
                float v = acc[i][j][r];
                if (addres) v += out[(size_t)og * S_ + sg];
                out[(size_t)og * S_ + sg] = v;
            }
        }
}

__global__ __launch_bounds__(256)
void final_kernel(void* __restrict__ out, const float* __restrict__ x0,
                  const float* __restrict__ x1, const void* __restrict__ ow,
                  const void* __restrict__ ob, const int* __restrict__ flag)
{
    __shared__ float wl[16][68];
    __shared__ float xl[16][68];
    const int isbf = flag[0];
    const int tid = threadIdx.x;
    const int tx = tid & 15, ty = tid >> 4;
    const int s0 = blockIdx.x * 64;
    const int o0 = blockIdx.y * 64;
    const int b  = blockIdx.z;
    float acc[4][4] = {};
    for (int c0 = 0; c0 < 2 * F_; c0 += 16) {
        if (isbf) {
            #pragma unroll
            for (int e = tid; e < 1024; e += 256) {
                int k = e & 15, o = e >> 4;
                wl[k][o] = __bfloat162float(((const bf16*)ow)[(size_t)(o0 + o) * (2 * F_) + (c0 + k)]);
            }
        } else {
            #pragma unroll
            for (int e = tid; e < 1024; e += 256) {
                int k = e & 15, o = e >> 4;
                wl[k][o] = ((const float*)ow)[(size_t)(o0 + o) * (2 * F_) + (c0 + k)];
            }
        }
        {
            int r = tid >> 4;
            int qq = (tid & 15) * 4;
            int cr = c0 + r;
            const float* src = (cr < F_) ? (x0 + ((size_t)b * F_ + cr) * S_)
                                         : (x1 + ((size_t)b * F_ + (cr - F_)) * S_);
            *(float4*)&xl[r][qq] = *(const float4*)(src + s0 + qq);
        }
        __syncthreads();
        #pragma unroll
        for (int k = 0; k < 16; ++k) {
            float4 av = *(const float4*)&wl[k][ty * 4];
            float4 bv = *(const float4*)&xl[k][tx * 4];
            #pragma unroll
            for (int i = 0; i < 4; ++i)
                #pragma unroll
                for (int j = 0; j < 4; ++j)
                    acc[i][j] += (&av.x)[i] * (&bv.x)[j];
        }
        __syncthreads();
    }
    #pragma unroll
    for (int i = 0; i < 4; ++i) {
        int o = o0 + ty * 4 + i;
        float bias = loadw(ob, o, isbf);
        size_t outoff = ((size_t)b * V_ + o) * S_ + s0 + tx * 4;
        if (isbf) {
            bf16* po = (bf16*)out + outoff;
            #pragma unroll
            for (int j = 0; j < 4; ++j)
                po[j] = __float2bfloat16(acc[i][j] + bias);
        } else {
            float* po = (float*)out + outoff;
            *(float4*)po = make_float4(acc[i][0] + bias, acc[i][1] + bias,
                                       acc[i][2] + bias, acc[i][3] + bias);
        }
    }
}

extern "C" void kernel_launch(void* const* d_in, const int* in_sizes, int n_in,
                              void* d_out, int out_size, void* d_ws, size_t ws_size,
                              hipStream_t stream)
{
    const int*  inp  = (const int*)d_in[0];
    const void* emb  = d_in[1];
    const void* w0   = d_in[2];
    const void* w1   = d_in[3];
    const void* w2   = d_in[4];
    const void* outw = d_in[5];
    const void* outb = d_in[6];

    const size_t NX = (size_t)B_ * F_ * S_;
    const size_t NT = (size_t)I3_ * S_;
    const size_t NV = (size_t)I_ * S_;
    const size_t VSTR = (size_t)VR_ * I_;     // vbt z-stride (elements)

    // P = batch slices processed per dispatch; pick largest fitting ws_size.
    // Vv is bf16 (2B).
    auto need = [&](int p) -> size_t {
        return 256 + 8 * NX + (size_t)4 * p * NT + (size_t)2 * p * NV
             + 2 * ((size_t)I3_ * KE_ + (size_t)p * VSTR + (size_t)p * S_ * F_
                    + (size_t)I3_ * F_ + (size_t)F_ * I_);
    };
    int P = 2;
    if (ws_size >= need(8)) P = 8;
    else if (ws_size >= need(4)) P = 4;

    int*   flag = (int*)d_ws;
    float* A  = (float*)d_ws + 64;
    float* Bb = A + NX;
    float* T  = Bb + NX;                       // P slices, fp32 (pre-mished)
    bf16*  Vv = (bf16*)(T + (size_t)P * NT);   // P slices, bf16
    bf16*  wexp = Vv + (size_t)P * NV;
    bf16*  vbt  = wexp + (size_t)I3_ * KE_;    // P slices, 6-row zero pad each
    bf16*  xbt  = vbt + (size_t)P * VSTR;      // P slices
    bf16*  wb0  = xbt + (size_t)P * S_ * F_;
    bf16*  wb2  = wb0 + (size_t)I3_ * F_;

    detect_kernel<<<1, 256, 0, stream>>>(flag, (const unsigned short*)emb);
    embed_kernel<<<dim3((unsigned)(NX / 256)), 256, 0, stream>>>(A, Bb, inp, emb, flag);
    zeropad_kernel<<<dim3((P * 6 * I_ + 255) / 256), 256, 0, stream>>>(vbt, P);

    int swap = 0;
    for (int d = 0; d < D_; ++d) {
        wexp_kernel<<<dim3(I3_ * I_ / 256), 256, 0, stream>>>(
            wexp, w1, (size_t)d * I3_ * I_ * K_, flag);
        cvt_kernel<<<dim3(I3_ * F_ / 256), 256, 0, stream>>>(
            wb0, w0, (size_t)d * I3_ * F_, I3_ * F_, flag);
        cvt_kernel<<<dim3(F_ * I_ / 256), 256, 0, stream>>>(
            wb2, w2, (size_t)d * F_ * I_, F_ * I_, flag);
        for (int bp = 0; bp < B_ / P; ++bp) {
            float* x0 = (swap ? Bb : A) + (size_t)(P * bp) * F_ * S_;
            float* x1 = (swap ? A : Bb) + (size_t)(P * bp) * F_ * S_;
            // xbt[z] = x1(b)^T bf16
            trans_kernel<<<dim3(S_ / 64, F_ / 64, P), 256, 0, stream>>>(
                xbt, (size_t)S_ * F_, x1, (size_t)F_ * S_, F_);
            // T[z] = mish(wb0 @ xbt[z])   (128x256-tile, grid 16*12*P)
            gemm128x256_kernel<<<dim3(S_ / 256, I3_ / 128, P), 512, 0, stream>>>(
                T, NT, wb0, F_, xbt, (size_t)S_ * F_, F_, F_, 0, 1);
            scan_kernel<<<dim3(I_, P), 256, 0, stream>>>(Vv, T);
            // vbt[z] rows 6.. = Vv[z]^T (pad rows 0..5 stay zero)
            transb_kernel<<<dim3(S_ / 64, I_ / 64, P), 256, 0, stream>>>(
                vbt + 6 * I_, VSTR, Vv, NV, I_);
            // T[z] = mish(causal conv as flattened-K GEMM)
            gemm128x256_kernel<<<dim3(S_ / 256, I3_ / 128, P), 512, 0, stream>>>(
                T, NT, wexp, KE_, vbt, VSTR, I_, KE_, 1, 1);
            scan_kernel<<<dim3(I_, P), 256, 0, stream>>>(Vv, T);
            transb_kernel<<<dim3(S_ / 64, I_ / 64, P), 256, 0, stream>>>(
                vbt + 6 * I_, VSTR, Vv, NV, I_);
            // x0(b) += wb2 @ v[z]   (small M=256: keep 128-tile kernel, grid 256)
            gemm128_kernel<<<dim3(S_ / 128, F_ / 128, P), 256, 0, stream>>>(
                x0, (size_t)F_ * S_, wb2, I_, vbt + 6 * I_, VSTR, I_, I_, 0, 1);
        }
        swap ^= 1;
    }
    final_kernel<<<dim3(S_ / 64, V_ / 64, B_), 256, 0, stream>>>(d_out, A, Bb, outw, outb, flag);
    (void)in_sizes; (void)n_in; (void)out_size;
}

// Round 5
// 2821.718 us; speedup vs baseline: 1.1590x; 1.1590x over previous
//
#include <hip/hip_runtime.h>
#include <hip/hip_bf16.h>

#define B_ 8
#define S_ 4096
#define F_ 256
#define I_ 512
#define D_ 4
#define K_ 7
#define V_ 256
#define I3_ 1536
#define KE_ 3584           // 7*512 flattened causal-conv K
#define VR_ (S_ + 8)       // vbt rows: 6 zero-pad + 4096 + 2 slack

using bf16 = __hip_bfloat16;
typedef __bf16 bf16x8 __attribute__((ext_vector_type(8)));
typedef float  f32x4  __attribute__((ext_vector_type(4)));

#define LDS_PTR(p) ((__attribute__((address_space(3))) void*)(p))
#define GLB_PTR(p) ((const __attribute__((address_space(1))) void*)(p))

// mish(x) = x*tanh(softplus(x)) = x*(u^2+2u)/(u^2+2u+2), u=e^x (exact closed form).
__device__ __forceinline__ float mishf(float x) {
    float u = expf(fminf(x, 30.0f));
    float t = u * (u + 2.0f);
    return x * (t / (t + 2.0f));
}

__device__ __forceinline__ float loadw(const void* p, size_t i, int isbf) {
    return isbf ? __bfloat162float(((const bf16*)p)[i]) : ((const float*)p)[i];
}

__device__ __forceinline__ __bf16 tobf(float x) {
    bf16 h = __float2bfloat16(x);
    return *(__bf16*)&h;
}

// bf16 buffers of small weights never show bf16-exponent>=132 (|x|>=32);
// fp32 buffers read as uint16 do (random mantissa bits in low halves).
__global__ __launch_bounds__(256)
void detect_kernel(int* __restrict__ flag, const unsigned short* __restrict__ p)
{
    __shared__ int sh[256];
    int cnt = 0;
    for (int j = threadIdx.x; j < 16384; j += 256) {
        unsigned int e = (p[j] >> 7) & 0xffu;
        if (e >= 132u) cnt++;
    }
    sh[threadIdx.x] = cnt;
    __syncthreads();
    for (int s = 128; s > 0; s >>= 1) {
        if ((int)threadIdx.x < s) sh[threadIdx.x] += sh[threadIdx.x + s];
        __syncthreads();
    }
    if (threadIdx.x == 0) flag[0] = (sh[0] == 0) ? 1 : 0;   // 1 => bf16 inputs
}

__global__ __launch_bounds__(256)
void embed_kernel(float* __restrict__ x0, float* __restrict__ x1,
                  const int* __restrict__ inp, const void* __restrict__ emb,
                  const int* __restrict__ flag)
{
    const int isbf = flag[0];
    size_t idx = (size_t)blockIdx.x * 256 + threadIdx.x;   // over B*F*S
    int s = (int)(idx % S_);
    int f = (int)((idx / S_) % F_);
    int b = (int)(idx / ((size_t)S_ * F_));
    int tok = inp[b * S_ + s];
    x0[idx] = loadw(emb, (size_t)tok * (2 * F_) + f, isbf);
    x1[idx] = loadw(emb, (size_t)tok * (2 * F_) + F_ + f, isbf);
}

// generic dtype-cast copy: dst[i] = (bf16)src[soff + i]
__global__ __launch_bounds__(256)
void cvt_kernel(bf16* __restrict__ dst, const void* __restrict__ src,
                size_t soff, int n, const int* __restrict__ flag)
{
    const int isbf = flag[0];
    int i = blockIdx.x * 256 + threadIdx.x;
    if (i < n) dst[i] = __float2bfloat16(loadw(src, soff + i, isbf));
}

// zero the 6 pad rows of all P vbt slices (re-poisoned every call)
__global__ __launch_bounds__(256)
void zeropad_kernel(bf16* __restrict__ vbt, int nslice)
{
    int i = blockIdx.x * 256 + threadIdx.x;
    if (i < nslice * 6 * I_) {
        int z = i / (6 * I_), off = i % (6 * I_);
        vbt[(size_t)z * VR_ * I_ + off] = __float2bfloat16(0.0f);
    }
}

// Inputs t are PRE-MISHED by the gemm epilogue.
// v[i,s] = cumsum_s(t[i,s])/(s+1) * t[I+i,s] + t[2I+i,s]; bf16 output.
// grid (I_, P): blockIdx.y = z scratch slice
__global__ __launch_bounds__(256)
void scan_kernel(bf16* __restrict__ vout, const float* __restrict__ t)
{
    const int z = blockIdx.y;
    const int i = blockIdx.x;
    t    += (size_t)z * I3_ * S_;
    vout += (size_t)z * I_ * S_;
    const float* dp  = t + (size_t)i * S_;
    const float* scp = dp + (size_t)I_ * S_;
    const float* shp = dp + (size_t)(2 * I_) * S_;
    bf16* op = vout + (size_t)i * S_;
    const int tid = threadIdx.x;
    const int base = tid * 16;

    float md[16];
    float lsum = 0.f;
    #pragma unroll
    for (int q = 0; q < 4; ++q) {
        float4 dv = *(const float4*)(dp + base + q * 4);
        #pragma unroll
        for (int j = 0; j < 4; ++j) {
            float m = (&dv.x)[j];
            md[q * 4 + j] = m;
            lsum += m;
        }
    }
    float ssum = lsum;
    #pragma unroll
    for (int off = 1; off < 64; off <<= 1) {
        float nv = __shfl_up(ssum, off, 64);
        if ((tid & 63) >= off) ssum += nv;
    }
    __shared__ float wtot[4];
    const int wid = tid >> 6, lane = tid & 63;
    if (lane == 63) wtot[wid] = ssum;
    __syncthreads();
    float excl = ssum - lsum;
    #pragma unroll
    for (int wq = 0; wq < 3; ++wq)
        if (wq < wid) excl += wtot[wq];

    float run = excl;
    bf16x8 o0v, o1v;
    #pragma unroll
    for (int q = 0; q < 4; ++q) {
        float4 scv = *(const float4*)(scp + base + q * 4);
        float4 shv = *(const float4*)(shp + base + q * 4);
        #pragma unroll
        for (int j = 0; j < 4; ++j) {
            run += md[q * 4 + j];
            float sdiv = (float)(base + q * 4 + j + 1);
            float ov = run / sdiv * (&scv.x)[j] + (&shv.x)[j];
            if (q < 2) o0v[q * 4 + j] = tobf(ov);
            else       o1v[(q - 2) * 4 + j] = tobf(ov);
        }
    }
    *(bf16x8*)(void*)(op + base) = o0v;
    *(bf16x8*)(void*)(op + base + 8) = o1v;
}

// w1 [o][c][k] (k innermost) -> wexp [o][k*512+c] bf16 (flattened-K A matrix)
__global__ __launch_bounds__(256)
void wexp_kernel(bf16* __restrict__ wexp, const void* __restrict__ w1,
                 size_t woff, const int* __restrict__ flag)
{
    const int isbf = flag[0];
    int idx = blockIdx.x * 256 + threadIdx.x;      // over 1536*512
    int c = idx & 511, o = idx >> 9;
    const size_t base = woff + ((size_t)o * 512 + c) * 7;
    float vals[7];
    #pragma unroll
    for (int k = 0; k < 7; ++k) vals[k] = loadw(w1, base + k, isbf);
    #pragma unroll
    for (int k = 0; k < 7; ++k)
        wexp[(size_t)o * KE_ + (k << 9) + c] = __float2bfloat16(vals[k]);
}

// src fp32 [C][S_] (+z*szstr) -> dst bf16 [S_][C] (+z*dzstr); 64x64 LDS tile
__global__ __launch_bounds__(256)
void trans_kernel(bf16* __restrict__ dst, size_t dzstr,
                  const float* __restrict__ src, size_t szstr, int C)
{
    __shared__ __align__(16) bf16 lt[64][72];
    const int z = blockIdx.z;
    dst += (size_t)z * dzstr;
    src += (size_t)z * szstr;
    const int tid = threadIdx.x;
    const int s0 = blockIdx.x * 64;
    const int c0 = blockIdx.y * 64;
    #pragma unroll
    for (int p = 0; p < 4; ++p) {
        int c = p * 16 + (tid >> 4);
        int sc = (tid & 15) * 4;
        float4 f = *(const float4*)(src + (size_t)(c0 + c) * S_ + s0 + sc);
        #pragma unroll
        for (int j = 0; j < 4; ++j)
            lt[sc + j][c] = __float2bfloat16((&f.x)[j]);
    }
    __syncthreads();
    #pragma unroll
    for (int p = 0; p < 2; ++p) {
        int ch = p * 256 + tid;
        int r = ch >> 3, g = ch & 7;
        *(bf16x8*)(dst + (size_t)(s0 + r) * C + c0 + g * 8) =
            *(const bf16x8*)&lt[r][g * 8];
    }
}

// src bf16 [C][S_] (+z*szstr) -> dst bf16 [S_][C] (+z*dzstr); 64x64 LDS tile
__global__ __launch_bounds__(256)
void transb_kernel(bf16* __restrict__ dst, size_t dzstr,
                   const bf16* __restrict__ src, size_t szstr, int C)
{
    __shared__ __align__(16) bf16 lt[64][72];
    const int z = blockIdx.z;
    dst += (size_t)z * dzstr;
    src += (size_t)z * szstr;
    const int tid = threadIdx.x;
    const int s0 = blockIdx.x * 64;
    const int c0 = blockIdx.y * 64;
    #pragma unroll
    for (int p = 0; p < 2; ++p) {
        int c = p * 32 + (tid >> 3);
        int sc = (tid & 7) * 8;
        bf16x8 v = *(const bf16x8*)(src + (size_t)(c0 + c) * S_ + s0 + sc);
        #pragma unroll
        for (int j = 0; j < 8; ++j)
            *(__bf16*)&lt[sc + j][c] = v[j];
    }
    __syncthreads();
    #pragma unroll
    for (int p = 0; p < 2; ++p) {
        int ch = p * 256 + tid;
        int r = ch >> 3, g = ch & 7;
        *(bf16x8*)(dst + (size_t)(s0 + r) * C + c0 + g * 8) =
            *(const bf16x8*)&lt[r][g * 8];
    }
}

// ---------------------------------------------------------------------------
// 192(o) x 256(s) tile GEMM, double-buffered LDS, 4 phases per K-tile (BK=64).
// Grid = (S/256) x (I3/192) x P = 16 x 8 x 4 = 512: EXACT 2 rounds over 256
// CUs (no tail).  8 waves (2M x 4N); per-wave 96o x 64s; acc[6][4] (96 AGPR).
// Phase = {ds_read (7 or 3) || stage (0-3 global_load_lds) || barrier ||
// lgkmcnt(0) || setprio 12xMFMA || barrier}  (m201-style fine interleave —
// R4's coarse 1-barrier variant measured -20%, matching m196).
// Per-CU per phase: LDS 672/288 cyc vs MFMA 466 -> balanced per tile
// (LDS 1920 ~ MFMA 1862).  Stage loads for tile t+1 (7) spread over phases
// 1-3; single vmcnt(0) before the tile's final barrier (last stage issued
// >=1.2 phases ~600+ cyc earlier; panels are L2-resident).
// WAR: buf n=(t+1)&1's last readers are tile t-1's ds_reads, drained at
// t-1's ph4 lgkm+barrier; restages issue after that barrier.
// RAW: buf c's loads awaited at t-1's vmcnt(0), published by its barrier.
// domish: fused mish on the fp32 result (feeds scan_kernel).
// ---------------------------------------------------------------------------
__global__ __launch_bounds__(512, 1)
void gemm192_kernel(float* __restrict__ out, size_t ozstr,
                    const bf16* __restrict__ Aw, int lda,
                    const bf16* __restrict__ Bm, size_t bzstr, int ldb,
                    int Kdim, int conv, int domish)
{
    __shared__ __align__(16) bf16 la[2][192][64];   // 48 KiB
    __shared__ __align__(16) bf16 lb[2][256][64];   // 64 KiB  (112 total)
    const int tid = threadIdx.x;
    const int s0 = blockIdx.x * 256;
    const int o0 = blockIdx.y * 192;
    const int z  = blockIdx.z;
    out += (size_t)z * ozstr;
    Bm  += (size_t)z * bzstr;
    const int wv = tid >> 6, lane = tid & 63;
    const int wr = wv >> 2, wc = wv & 3;            // 2(M) x 4(N) waves
    const int l16 = lane & 15, q = lane >> 4;
    const int srow = lane >> 3;                     // staging row within 8-row strip
    const int schunk = (lane & 7) ^ srow;           // pre-swizzled source chunk
    const int nKt = Kdim >> 6;

    f32x4 acc[6][4];
    #pragma unroll
    for (int i = 0; i < 6; ++i)
        #pragma unroll
        for (int j = 0; j < 4; ++j)
            #pragma unroll
            for (int r = 0; r < 4; ++r) acc[i][j][r] = 0.f;

#define STAGE_A3(buf, kt) do {                                                \
    const bf16* gpA_ = Aw + (size_t)(o0 + wv * 8 + srow) * lda                \
                          + ((kt) << 6) + (schunk << 3);                      \
    __builtin_amdgcn_global_load_lds(GLB_PTR(gpA_),                           \
        LDS_PTR(&la[buf][wv * 8][0]), 16, 0, 0);                              \
    __builtin_amdgcn_global_load_lds(GLB_PTR(gpA_ + (size_t)64 * lda),        \
        LDS_PTR(&la[buf][64 + wv * 8][0]), 16, 0, 0);                         \
    __builtin_amdgcn_global_load_lds(GLB_PTR(gpA_ + (size_t)128 * lda),       \
        LDS_PTR(&la[buf][128 + wv * 8][0]), 16, 0, 0);                        \
} while (0)

#define STAGE_BL(buf, l, ro, bk) do {                                         \
    const bf16* gpB_ = Bm + (size_t)(s0 + (l) * 64 + wv * 8 + srow + (ro)) * ldb \
                          + (bk) + (schunk << 3);                             \
    __builtin_amdgcn_global_load_lds(GLB_PTR(gpB_),                           \
        LDS_PTR(&lb[buf][(l) * 64 + wv * 8][0]), 16, 0, 0);                   \
} while (0)

#define LDAF3(buf, kk, ih) do {                                               \
    _Pragma("unroll") for (int i2 = 0; i2 < 3; ++i2) {                        \
        int r_ = wr * 96 + (ih) * 48 + i2 * 16 + l16;                         \
        af[i2] = *(const bf16x8*)&la[buf][r_][(((kk) * 4 + q) ^ (r_ & 7)) << 3]; \
    }                                                                         \
} while (0)

#define LDBF4(buf, kk) do {                                                   \
    _Pragma("unroll") for (int j2 = 0; j2 < 4; ++j2) {                        \
        int r_ = wc * 64 + j2 * 16 + l16;                                     \
        bfr[j2] = *(const bf16x8*)&lb[buf][r_][(((kk) * 4 + q) ^ (r_ & 7)) << 3]; \
    }                                                                         \
} while (0)

#define MFMA12(ih) do {                                                       \
    __builtin_amdgcn_s_setprio(1);                                            \
    _Pragma("unroll") for (int i2 = 0; i2 < 3; ++i2)                          \
    _Pragma("unroll") for (int j2 = 0; j2 < 4; ++j2)                          \
        acc[(ih) * 3 + i2][j2] = __builtin_amdgcn_mfma_f32_16x16x32_bf16(     \
            af[i2], bfr[j2], acc[(ih) * 3 + i2][j2], 0, 0, 0);                \
    __builtin_amdgcn_s_setprio(0);                                            \
} while (0)

#define BARR()  __builtin_amdgcn_s_barrier()
#define WLGKM() asm volatile("s_waitcnt lgkmcnt(0)" ::: "memory")
#define WVM0()  asm volatile("s_waitcnt vmcnt(0)" ::: "memory")

    // prologue: stage tile 0 -> buf0 (7 loads), land, publish
    STAGE_A3(0, 0);
    STAGE_BL(0, 0, 0, 0); STAGE_BL(0, 1, 0, 0);
    STAGE_BL(0, 2, 0, 0); STAGE_BL(0, 3, 0, 0);
    WVM0();
    BARR();

    bf16x8 af[3], bfr[4];
    for (int t = 0; t < nKt; ++t) {
        const int c = t & 1, n = c ^ 1;
        const bool st = (t + 1) < nKt;
        int ro1 = 0, bk1 = (t + 1) << 6;
        if (conv) { ro1 = bk1 >> 9; bk1 &= 511; }
        // ---- phase 1 (kk0, ihalf0): 7 reads; stage A(t+1) 3 loads
        LDAF3(c, 0, 0); LDBF4(c, 0);
        if (st) STAGE_A3(n, t + 1);
        BARR(); WLGKM();
        MFMA12(0);
        BARR();
        // ---- phase 2 (kk0, ihalf1): 3 reads; stage B(t+1) loads 0,1
        LDAF3(c, 0, 1);
        if (st) { STAGE_BL(n, 0, ro1, bk1); STAGE_BL(n, 1, ro1, bk1); }
        BARR(); WLGKM();
        MFMA12(1);
        BARR();
        // ---- phase 3 (kk1, ihalf0): 7 reads; stage B(t+1) loads 2,3
        LDAF3(c, 1, 0); LDBF4(c, 1);
        if (st) { STAGE_BL(n, 2, ro1, bk1); STAGE_BL(n, 3, ro1, bk1); }
        BARR(); WLGKM();
        MFMA12(0);
        BARR();
        // ---- phase 4 (kk1, ihalf1): 3 reads; wait tile t+1 landed; publish
        LDAF3(c, 1, 1);
        BARR(); WLGKM();
        MFMA12(1);
        WVM0();
        BARR();
    }

    // C/D: col(lane&15)=s, row(q*4+reg)=o   [verified convention]
    #pragma unroll
    for (int i = 0; i < 6; ++i)
        #pragma unroll
        for (int j = 0; j < 4; ++j) {
            int sg = s0 + wc * 64 + j * 16 + l16;
            #pragma unroll
            for (int r = 0; r < 4; ++r) {
                int og = o0 + wr * 96 + i * 16 + q * 4 + r;
                float v = acc[i][j][r];
                if (domish) v = mishf(v);
                out[(size_t)og * S_ + sg] = v;
            }
        }
#undef STAGE_A3
#undef STAGE_BL
#undef LDAF3
#undef LDBF4
#undef MFMA12
#undef BARR
#undef WLGKM
#undef WVM0
}

// 128x128 GEMM (m97 structure) kept for the small w2 conv (M=256) + accumulate.
__global__ __launch_bounds__(256)
void gemm128_kernel(float* __restrict__ out, size_t ozstr,
                    const bf16* __restrict__ Aw, int lda,
                    const bf16* __restrict__ Bm, size_t bzstr, int ldb,
                    int Kdim, int conv, int addres)
{
    __shared__ __align__(16) bf16 la[128][64];
    __shared__ __align__(16) bf16 lb[128][64];
    const int tid = threadIdx.x;
    const int s0 = blockIdx.x * 128;
    const int o0 = blockIdx.y * 128;
    const int z  = blockIdx.z;
    out += (size_t)z * ozstr;
    Bm  += (size_t)z * bzstr;
    const int wv = tid >> 6, lane = tid & 63;
    const int wo = wv & 1, wsv = wv >> 1;
    const int l16 = lane & 15, q = lane >> 4;
    const int lrow = lane >> 3, lslot = lane & 7;

    f32x4 acc[4][4];
    #pragma unroll
    for (int i = 0; i < 4; ++i)
        #pragma unroll
        for (int j = 0; j < 4; ++j)
            #pragma unroll
            for (int r = 0; r < 4; ++r) acc[i][j][r] = 0.f;

    for (int k0 = 0; k0 < Kdim; k0 += 64) {
        int roff = 0, bk = k0;
        if (conv) { roff = k0 >> 9; bk = k0 & 511; }
        __syncthreads();
        #pragma unroll
        for (int t = 0; t < 4; ++t) {
            int rbase = wv * 32 + t * 8;
            int row = rbase + lrow;
            int chunk = lslot ^ (row & 7);
            __builtin_amdgcn_global_load_lds(
                GLB_PTR(Aw + (size_t)(o0 + row) * lda + k0 + chunk * 8),
                LDS_PTR(&la[rbase][0]), 16, 0, 0);
        }
        #pragma unroll
        for (int t = 0; t < 4; ++t) {
            int rbase = wv * 32 + t * 8;
            int row = rbase + lrow;
            int chunk = lslot ^ (row & 7);
            __builtin_amdgcn_global_load_lds(
                GLB_PTR(Bm + (size_t)(s0 + row + roff) * ldb + bk + chunk * 8),
                LDS_PTR(&lb[rbase][0]), 16, 0, 0);
        }
        __syncthreads();
        #pragma unroll
        for (int kk = 0; kk < 2; ++kk) {
            bf16x8 af[4], bfr[4];
            #pragma unroll
            for (int i = 0; i < 4; ++i) {
                int r = wo * 64 + i * 16 + l16;
                int c = kk * 4 + q;
                af[i] = *(const bf16x8*)&la[r][(c ^ (r & 7)) * 8];
            }
            #pragma unroll
            for (int j = 0; j < 4; ++j) {
                int r = wsv * 64 + j * 16 + l16;
                int c = kk * 4 + q;
                bfr[j] = *(const bf16x8*)&lb[r][(c ^ (r & 7)) * 8];
            }
            #pragma unroll
            for (int i = 0; i < 4; ++i)
                #pragma unroll
                for (int j = 0; j < 4; ++j)
                    acc[i][j] = __builtin_amdgcn_mfma_f32_16x16x32_bf16(
                        af[i], bfr[j], acc[i][j], 0, 0, 0);
        }
    }
    #pragma unroll
    for (int i = 0; i < 4; ++i)
        #pragma unroll
        for (int j = 0; j < 4; ++j) {
            int sg = s0 + wsv * 64 + j * 16 + l16;
            #pragma unroll
            for (int r = 0; r < 4; ++r) {
                int og = o0 + wo * 64 + i * 16 + q * 4 + r;
                float v = acc[i][j][r];
                if (addres) v += out[(size_t)og * S_ + sg];
                out[(size_t)og * S_ + sg] = v;
            }
        }
}

__global__ __launch_bounds__(256)
void final_kernel(void* __restrict__ out, const float* __restrict__ x0,
                  const float* __restrict__ x1, const void* __restrict__ ow,
                  const void* __restrict__ ob, const int* __restrict__ flag)
{
    __shared__ float wl[16][68];
    __shared__ float xl[16][68];
    const int isbf = flag[0];
    const int tid = threadIdx.x;
    const int tx = tid & 15, ty = tid >> 4;
    const int s0 = blockIdx.x * 64;
    const int o0 = blockIdx.y * 64;
    const int b  = blockIdx.z;
    float acc[4][4] = {};
    for (int c0 = 0; c0 < 2 * F_; c0 += 16) {
        if (isbf) {
            #pragma unroll
            for (int e = tid; e < 1024; e += 256) {
                int k = e & 15, o = e >> 4;
                wl[k][o] = __bfloat162float(((const bf16*)ow)[(size_t)(o0 + o) * (2 * F_) + (c0 + k)]);
            }
        } else {
            #pragma unroll
            for (int e = tid; e < 1024; e += 256) {
                int k = e & 15, o = e >> 4;
                wl[k][o] = ((const float*)ow)[(size_t)(o0 + o) * (2 * F_) + (c0 + k)];
            }
        }
        {
            int r = tid >> 4;
            int qq = (tid & 15) * 4;
            int cr = c0 + r;
            const float* src = (cr < F_) ? (x0 + ((size_t)b * F_ + cr) * S_)
                                         : (x1 + ((size_t)b * F_ + (cr - F_)) * S_);
            *(float4*)&xl[r][qq] = *(const float4*)(src + s0 + qq);
        }
        __syncthreads();
        #pragma unroll
        for (int k = 0; k < 16; ++k) {
            float4 av = *(const float4*)&wl[k][ty * 4];
            float4 bv = *(const float4*)&xl[k][tx * 4];
            #pragma unroll
            for (int i = 0; i < 4; ++i)
                #pragma unroll
                for (int j = 0; j < 4; ++j)
                    acc[i][j] += (&av.x)[i] * (&bv.x)[j];
        }
        __syncthreads();
    }
    #pragma unroll
    for (int i = 0; i < 4; ++i) {
        int o = o0 + ty * 4 + i;
        float bias = loadw(ob, o, isbf);
        size_t outoff = ((size_t)b * V_ + o) * S_ + s0 + tx * 4;
        if (isbf) {
            bf16* po = (bf16*)out + outoff;
            #pragma unroll
            for (int j = 0; j < 4; ++j)
                po[j] = __float2bfloat16(acc[i][j] + bias);
        } else {
            float* po = (float*)out + outoff;
            *(float4*)po = make_float4(acc[i][0] + bias, acc[i][1] + bias,
                                       acc[i][2] + bias, acc[i][3] + bias);
        }
    }
}

extern "C" void kernel_launch(void* const* d_in, const int* in_sizes, int n_in,
                              void* d_out, int out_size, void* d_ws, size_t ws_size,
                              hipStream_t stream)
{
    const int*  inp  = (const int*)d_in[0];
    const void* emb  = d_in[1];
    const void* w0   = d_in[2];
    const void* w1   = d_in[3];
    const void* w2   = d_in[4];
    const void* outw = d_in[5];
    const void* outb = d_in[6];

    const size_t NX = (size_t)B_ * F_ * S_;
    const size_t NT = (size_t)I3_ * S_;
    const size_t NV = (size_t)I_ * S_;
    const size_t VSTR = (size_t)VR_ * I_;     // vbt z-stride (elements)

    // P = batch slices processed per dispatch; pick largest fitting ws_size.
    auto need = [&](int p) -> size_t {
        return 256 + 8 * NX + (size_t)4 * p * NT + (size_t)2 * p * NV
             + 2 * ((size_t)I3_ * KE_ + (size_t)p * VSTR + (size_t)p * S_ * F_
                    + (size_t)I3_ * F_ + (size_t)F_ * I_);
    };
    int P = 2;
    if (ws_size >= need(8)) P = 8;
    else if (ws_size >= need(4)) P = 4;

    int*   flag = (int*)d_ws;
    float* A  = (float*)d_ws + 64;
    float* Bb = A + NX;
    float* T  = Bb + NX;                       // P slices, fp32 (pre-mished)
    bf16*  Vv = (bf16*)(T + (size_t)P * NT);   // P slices, bf16
    bf16*  wexp = Vv + (size_t)P * NV;
    bf16*  vbt  = wexp + (size_t)I3_ * KE_;    // P slices, 6-row zero pad each
    bf16*  xbt  = vbt + (size_t)P * VSTR;      // P slices
    bf16*  wb0  = xbt + (size_t)P * S_ * F_;
    bf16*  wb2  = wb0 + (size_t)I3_ * F_;

    detect_kernel<<<1, 256, 0, stream>>>(flag, (const unsigned short*)emb);
    embed_kernel<<<dim3((unsigned)(NX / 256)), 256, 0, stream>>>(A, Bb, inp, emb, flag);
    zeropad_kernel<<<dim3((P * 6 * I_ + 255) / 256), 256, 0, stream>>>(vbt, P);

    int swap = 0;
    for (int d = 0; d < D_; ++d) {
        wexp_kernel<<<dim3(I3_ * I_ / 256), 256, 0, stream>>>(
            wexp, w1, (size_t)d * I3_ * I_ * K_, flag);
        cvt_kernel<<<dim3(I3_ * F_ / 256), 256, 0, stream>>>(
            wb0, w0, (size_t)d * I3_ * F_, I3_ * F_, flag);
        cvt_kernel<<<dim3(F_ * I_ / 256), 256, 0, stream>>>(
            wb2, w2, (size_t)d * F_ * I_, F_ * I_, flag);
        for (int bp = 0; bp < B_ / P; ++bp) {
            float* x0 = (swap ? Bb : A) + (size_t)(P * bp) * F_ * S_;
            float* x1 = (swap ? A : Bb) + (size_t)(P * bp) * F_ * S_;
            // xbt[z] = x1(b)^T bf16
            trans_kernel<<<dim3(S_ / 64, F_ / 64, P), 256, 0, stream>>>(
                xbt, (size_t)S_ * F_, x1, (size_t)F_ * S_, F_);
            // T[z] = mish(wb0 @ xbt[z])   (192x256-tile, grid 16*8*P = 512)
            gemm192_kernel<<<dim3(S_ / 256, I3_ / 192, P), 512, 0, stream>>>(
                T, NT, wb0, F_, xbt, (size_t)S_ * F_, F_, F_, 0, 1);
            scan_kernel<<<dim3(I_, P), 256, 0, stream>>>(Vv, T);
            // vbt[z] rows 6.. = Vv[z]^T (pad rows 0..5 stay zero)
            transb_kernel<<<dim3(S_ / 64, I_ / 64, P), 256, 0, stream>>>(
                vbt + 6 * I_, VSTR, Vv, NV, I_);
            // T[z] = mish(causal conv as flattened-K GEMM)
            gemm192_kernel<<<dim3(S_ / 256, I3_ / 192, P), 512, 0, stream>>>(
                T, NT, wexp, KE_, vbt, VSTR, I_, KE_, 1, 1);
            scan_kernel<<<dim3(I_, P), 256, 0, stream>>>(Vv, T);
            transb_kernel<<<dim3(S_ / 64, I_ / 64, P), 256, 0, stream>>>(
                vbt + 6 * I_, VSTR, Vv, NV, I_);
            // x0(b) += wb2 @ v[z]   (small M=256: keep 128-tile kernel, grid 256)
            gemm128_kernel<<<dim3(S_ / 128, F_ / 128, P), 256, 0, stream>>>(
                x0, (size_t)F_ * S_, wb2, I_, vbt + 6 * I_, VSTR, I_, I_, 0, 1);
        }
        swap ^= 1;
    }
    final_kernel<<<dim3(S_ / 64, V_ / 64, B_), 256, 0, stream>>>(d_out, A, Bb, outw, outb, flag);
    (void)in_sizes; (void)n_in; (void)out_size;
}